// Round 1
// baseline (280.412 us; speedup 1.0000x reference)
//
#include <hip/hip_runtime.h>
#include <hip/hip_bf16.h>

#define D_DIM 1024
#define L_DIM 8
#define T_DIM 2048
#define B_DIM 4
#define TOKS  (B_DIM * T_DIM)                 // 8192
#define OUT_ELEMS ((size_t)TOKS * D_DIM)      // 8388608
#define EPSF 1e-6f

__device__ __forceinline__ float wave_sum(float v) {
#pragma unroll
    for (int off = 32; off; off >>= 1) v += __shfl_xor(v, off, 64);
    return v;
}

__device__ __forceinline__ float dot4(const float4& a, const float4& b) {
    return a.x * b.x + a.y * b.y + a.z * b.z + a.w * b.w;
}

// ---------------------------------------------------------------------------
// Kernel A: per-token rms scale of h_base:  scales[t] = rsqrt(mean(h^2)+eps)
// One wave per token; 4 tokens per 256-thread block.
// ---------------------------------------------------------------------------
__global__ __launch_bounds__(256) void k_scales(const float* __restrict__ h,
                                                float* __restrict__ scales) {
    int tok  = blockIdx.x * 4 + (threadIdx.x >> 6);
    int lane = threadIdx.x & 63;
    const float4* row = (const float4*)(h + (size_t)tok * D_DIM);
    float ssq = 0.f;
#pragma unroll
    for (int k = 0; k < 4; ++k) {
        float4 v = row[lane + k * 64];
        ssq += dot4(v, v);
    }
    ssq = wave_sum(ssq);
    if (lane == 0) scales[tok] = rsqrtf(ssq * (1.f / D_DIM) + EPSF);
}

// ---------------------------------------------------------------------------
// Kernel B: q[t][d] = query[d] + sum_j Wu[d][j] * r[t][j]
//           r[t][j] = scales[t] * sum_d h[t][d]*qnorm_w[d]*Wd[j][d]
// 64-token tiles, 128 blocks, 256 threads. Register-tiled f32 GEMM1 (K=1024)
// then GEMM2 (K=64) with r tile in LDS.
// ---------------------------------------------------------------------------
#define TT 64
__global__ __launch_bounds__(256) void k_q(const float* __restrict__ h,
                                           const float* __restrict__ scales,
                                           const float* __restrict__ query,
                                           const float* __restrict__ qnw,
                                           const float* __restrict__ Wd,
                                           const float* __restrict__ Wu,
                                           float* __restrict__ q) {
    __shared__ float a_lds[64][65];   // h chunk   [token][k]   (pad 65: conflict-free b32)
    __shared__ float b_lds[64][65];   // Wd' chunk [j][k]
    __shared__ float r_lds[64][68];   // r tile    [token][j]   (68: float4-aligned rows)

    int tid = threadIdx.x;
    int t0  = blockIdx.x * TT;
    int tr  = tid >> 4;               // 0..15  token group
    int tc  = tid & 15;               // 0..15  j group

    float acc[4][4];
#pragma unroll
    for (int i = 0; i < 4; ++i)
#pragma unroll
        for (int j = 0; j < 4; ++j) acc[i][j] = 0.f;

    for (int kc = 0; kc < 16; ++kc) {
        __syncthreads();
        // stage 64x64 chunks of h and Wd*qnorm_w
#pragma unroll
        for (int i = 0; i < 4; ++i) {
            int e   = i * 1024 + tid * 4;
            int row = e >> 6, col = e & 63;
            float4 av = *(const float4*)(h + (size_t)(t0 + row) * D_DIM + kc * 64 + col);
            a_lds[row][col + 0] = av.x; a_lds[row][col + 1] = av.y;
            a_lds[row][col + 2] = av.z; a_lds[row][col + 3] = av.w;
            float4 wv = *(const float4*)(Wd + (size_t)row * D_DIM + kc * 64 + col);
            float4 nv = *(const float4*)(qnw + kc * 64 + col);
            b_lds[row][col + 0] = wv.x * nv.x; b_lds[row][col + 1] = wv.y * nv.y;
            b_lds[row][col + 2] = wv.z * nv.z; b_lds[row][col + 3] = wv.w * nv.w;
        }
        __syncthreads();
#pragma unroll 4
        for (int kk = 0; kk < 64; ++kk) {
            float a[4], b[4];
#pragma unroll
            for (int i = 0; i < 4; ++i) a[i] = a_lds[tr * 4 + i][kk];
#pragma unroll
            for (int j = 0; j < 4; ++j) b[j] = b_lds[tc * 4 + j][kk];
#pragma unroll
            for (int i = 0; i < 4; ++i)
#pragma unroll
                for (int j = 0; j < 4; ++j) acc[i][j] += a[i] * b[j];
        }
    }
    __syncthreads();
    // r tile -> LDS with per-token scale
#pragma unroll
    for (int i = 0; i < 4; ++i) {
        float sc = scales[t0 + tr * 4 + i];
#pragma unroll
        for (int j = 0; j < 4; ++j) r_lds[tr * 4 + i][tc * 4 + j] = acc[i][j] * sc;
    }
    __syncthreads();

    // GEMM2: thread owns 4 d-rows of Wu (held in regs), loops 64 tokens
#pragma unroll
    for (int k = 0; k < 4; ++k) {
        int d = k * 256 + tid;
        float4 wu[16];
        const float4* wurow = (const float4*)(Wu + (size_t)d * 64);
#pragma unroll
        for (int m = 0; m < 16; ++m) wu[m] = wurow[m];
        float qd = query[d];
        for (int t = 0; t < TT; ++t) {
            float a2 = qd;
#pragma unroll
            for (int m = 0; m < 16; ++m) {
                float4 r4 = *(const float4*)&r_lds[t][m * 4];
                a2 += dot4(wu[m], r4);
            }
            q[(size_t)(t0 + t) * D_DIM + d] = a2;
        }
    }
}

// ---------------------------------------------------------------------------
// Kernel D: main fused kernel, one block per (b,t) token.
// Stages the 8 depth rows of prev in LDS (read prev ONCE from HBM),
// computes scores -> softmax(L) -> delta -> rmsnorm -> gated residual.
// ---------------------------------------------------------------------------
__global__ __launch_bounds__(256) void k_main(const float* __restrict__ h,
                                              const float* __restrict__ prev,
                                              const float* __restrict__ qbuf,
                                              const float* __restrict__ score_w,
                                              const float* __restrict__ out_w,
                                              const float* __restrict__ tg_w,
                                              const float* __restrict__ gate,
                                              const float* __restrict__ tg_b,
                                              float* __restrict__ out,
                                              float* __restrict__ alpha_out) {
    __shared__ __align__(16) float pl[L_DIM][D_DIM];  // 32 KB staged prev rows
    __shared__ float wred[2][L_DIM][4];
    __shared__ float gred[4];
    __shared__ float dred[4];

    int tid = threadIdx.x, lane = tid & 63, w = tid >> 6;
    int blk = blockIdx.x;
    int b   = blk >> 11;          // / T_DIM
    int t   = blk & (T_DIM - 1);
    size_t tok = (size_t)blk;

    float4 h4 = ((const float4*)(h + tok * D_DIM))[tid];
    float4 q4 = ((const float4*)(qbuf + tok * D_DIM))[tid];
    float4 sw = ((const float4*)score_w)[tid];
    float4 tw = ((const float4*)tg_w)[tid];

    // token gate partial
    float gp = wave_sum(dot4(h4, tw));
    if (lane == 0) gred[w] = gp;

    float4 qs;
    qs.x = q4.x * sw.x; qs.y = q4.y * sw.y; qs.z = q4.z * sw.z; qs.w = q4.w * sw.w;

#pragma unroll
    for (int l = 0; l < L_DIM; ++l) {
        float4 p = ((const float4*)(prev + ((size_t)((b * L_DIM + l) * T_DIM + t)) * D_DIM))[tid];
        ((float4*)pl[l])[tid] = p;
        float ssq = wave_sum(dot4(p, p));
        float dt  = wave_sum(dot4(p, qs));
        if (lane == 0) { wred[0][l][w] = ssq; wred[1][l][w] = dt; }
    }
    __syncthreads();

    // scores + softmax over L (all threads redundantly; 8 elements)
    float sc[L_DIM], mx = -1e30f;
#pragma unroll
    for (int l = 0; l < L_DIM; ++l) {
        float ssq = wred[0][l][0] + wred[0][l][1] + wred[0][l][2] + wred[0][l][3];
        float dt  = wred[1][l][0] + wred[1][l][1] + wred[1][l][2] + wred[1][l][3];
        sc[l] = dt * rsqrtf(ssq * (1.f / D_DIM) + EPSF);
        mx = fmaxf(mx, sc[l]);
    }
    float al[L_DIM], asum = 0.f;
#pragma unroll
    for (int l = 0; l < L_DIM; ++l) { al[l] = __expf(sc[l] - mx); asum += al[l]; }
    float inv = 1.f / asum;
#pragma unroll
    for (int l = 0; l < L_DIM; ++l) al[l] *= inv;

    float gd = gred[0] + gred[1] + gred[2] + gred[3];
    float g  = gate[0] / (1.f + __expf(-(gd + tg_b[0])));

    // delta = sum_l alpha_l * prev_l  (from LDS)
    float4 dl = make_float4(0.f, 0.f, 0.f, 0.f);
#pragma unroll
    for (int l = 0; l < L_DIM; ++l) {
        float4 p = ((const float4*)pl[l])[tid];
        dl.x += al[l] * p.x; dl.y += al[l] * p.y;
        dl.z += al[l] * p.z; dl.w += al[l] * p.w;
    }
    float dss = wave_sum(dot4(dl, dl));
    if (lane == 0) dred[w] = dss;
    __syncthreads();
    float dsum   = dred[0] + dred[1] + dred[2] + dred[3];
    float dscale = rsqrtf(dsum * (1.f / D_DIM) + EPSF);

    float4 ow = ((const float4*)out_w)[tid];
    float4 o;
    o.x = h4.x + g * dl.x * dscale * ow.x;
    o.y = h4.y + g * dl.y * dscale * ow.y;
    o.z = h4.z + g * dl.z * dscale * ow.z;
    o.w = h4.w + g * dl.w * dscale * ow.w;
    ((float4*)(out + tok * D_DIM))[tid] = o;

    if (tid < L_DIM)
        alpha_out[(size_t)b * (L_DIM * T_DIM) + tid * T_DIM + t] = al[tid];
}

extern "C" void kernel_launch(void* const* d_in, const int* in_sizes, int n_in,
                              void* d_out, int out_size, void* d_ws, size_t ws_size,
                              hipStream_t stream) {
    (void)in_sizes; (void)n_in; (void)out_size; (void)ws_size;
    const float* h       = (const float*)d_in[0];
    const float* prev    = (const float*)d_in[1];
    const float* query   = (const float*)d_in[2];
    const float* gate    = (const float*)d_in[3];
    const float* score_w = (const float*)d_in[4];
    const float* out_w   = (const float*)d_in[5];
    const float* qnw     = (const float*)d_in[6];
    const float* Wd      = (const float*)d_in[7];
    const float* Wu      = (const float*)d_in[8];
    const float* tg_w    = (const float*)d_in[9];
    const float* tg_b    = (const float*)d_in[10];

    float* out   = (float*)d_out;
    float* alpha = out + OUT_ELEMS;

    float* qbuf   = (float*)d_ws;            // 8192*1024 f32 = 32 MB
    float* scales = qbuf + OUT_ELEMS;        // 8192 f32

    k_scales<<<TOKS / 4, 256, 0, stream>>>(h, scales);
    k_q<<<TOKS / TT, 256, 0, stream>>>(h, scales, query, qnw, Wd, Wu, qbuf);
    k_main<<<TOKS, 256, 0, stream>>>(h, prev, qbuf, score_w, out_w, tg_w,
                                     gate, tg_b, out, alpha);
}

// Round 2
// 148.186 us; speedup vs baseline: 1.8923x; 1.8923x over previous
//
#include <hip/hip_runtime.h>
#include <hip/hip_bf16.h>

#define D_DIM 1024
#define L_DIM 8
#define T_DIM 2048
#define B_DIM 4
#define TOKS  (B_DIM * T_DIM)                 // 8192
#define OUT_ELEMS ((size_t)TOKS * D_DIM)      // 8388608
#define EPSF 1e-6f

#define KSPLIT 4
#define KCH    256            // K range per split
#define BK     32             // K chunk staged per iteration
#define G1_TT  64             // tokens per GEMM1 block

__device__ __forceinline__ float wave_sum(float v) {
#pragma unroll
    for (int off = 32; off; off >>= 1) v += __shfl_xor(v, off, 64);
    return v;
}

__device__ __forceinline__ float dot4(const float4& a, const float4& b) {
    return a.x * b.x + a.y * b.y + a.z * b.z + a.w * b.w;
}

__device__ __forceinline__ float bf2f(unsigned short u) {
    union { unsigned int i; float f; } x;
    x.i = ((unsigned int)u) << 16;
    return x.f;
}

// ---------------------------------------------------------------------------
// GEMM1 (split-K): r_part[ks][t][j] = sum_{k in ks-range} h[t][k]*qnw[k]*Wd[j][k]
// Also accumulates ssq_part[ks][t] = sum_{k in ks-range} h[t][k]^2 (raw h).
// grid (128, 4), 256 threads. k-major LDS, 4x4 register tile, b128 reads.
// ---------------------------------------------------------------------------
__global__ __launch_bounds__(256) void k_rproj(const float* __restrict__ h,
                                               const float* __restrict__ qnw,
                                               const float* __restrict__ Wd,
                                               float* __restrict__ r_part,
                                               float* __restrict__ ssq_part) {
    __shared__ float a_lds[BK][68];   // [k][token]
    __shared__ float b_lds[BK][68];   // [k][j]

    int tid  = threadIdx.x;
    int t0   = blockIdx.x * G1_TT;
    int ks   = blockIdx.y;
    int k0   = ks * KCH;

    int ldr = tid >> 2;               // 0..63 (token row / Wd row)
    int ldq = tid & 3;                // 0..3

    int tr = tid >> 4;                // 0..15 token group
    int tc = tid & 15;                // 0..15 j group

    float ssq = 0.f;
    float acc[4][4];
#pragma unroll
    for (int i = 0; i < 4; ++i)
#pragma unroll
        for (int j = 0; j < 4; ++j) acc[i][j] = 0.f;

    for (int kc = 0; kc < KCH; kc += BK) {
        __syncthreads();
        const float* hrow = h   + (size_t)(t0 + ldr) * D_DIM + k0 + kc;
        const float* wrow = Wd  + (size_t)ldr * D_DIM + k0 + kc;
        const float* nrow = qnw + k0 + kc;
#pragma unroll
        for (int p = 0; p < 2; ++p) {
            int f = ldq + p * 4;      // f4 index 0..7 within the 32-float chunk
            float4 av = *(const float4*)(hrow + f * 4);
            ssq += dot4(av, av);
            a_lds[f * 4 + 0][ldr] = av.x;
            a_lds[f * 4 + 1][ldr] = av.y;
            a_lds[f * 4 + 2][ldr] = av.z;
            a_lds[f * 4 + 3][ldr] = av.w;
            float4 wv = *(const float4*)(wrow + f * 4);
            float4 nv = *(const float4*)(nrow + f * 4);
            b_lds[f * 4 + 0][ldr] = wv.x * nv.x;
            b_lds[f * 4 + 1][ldr] = wv.y * nv.y;
            b_lds[f * 4 + 2][ldr] = wv.z * nv.z;
            b_lds[f * 4 + 3][ldr] = wv.w * nv.w;
        }
        __syncthreads();
#pragma unroll
        for (int kk = 0; kk < BK; ++kk) {
            float4 a4 = *(const float4*)&a_lds[kk][tr * 4];
            float4 b4 = *(const float4*)&b_lds[kk][tc * 4];
            float a[4] = {a4.x, a4.y, a4.z, a4.w};
            float b[4] = {b4.x, b4.y, b4.z, b4.w};
#pragma unroll
            for (int i = 0; i < 4; ++i)
#pragma unroll
                for (int j = 0; j < 4; ++j) acc[i][j] += a[i] * b[j];
        }
    }

    // ssq partial: 4 threads (ldq) share one token -> reduce within 4 lanes
    ssq += __shfl_xor(ssq, 1, 64);
    ssq += __shfl_xor(ssq, 2, 64);
    if (ldq == 0) ssq_part[(size_t)ks * TOKS + t0 + ldr] = ssq;

    // store r partials
#pragma unroll
    for (int i = 0; i < 4; ++i) {
        float4 v = make_float4(acc[i][0], acc[i][1], acc[i][2], acc[i][3]);
        *(float4*)(r_part + ((size_t)ks * TOKS + t0 + tr * 4 + i) * 64 + tc * 4) = v;
    }
}

// ---------------------------------------------------------------------------
// GEMM2: qs[t][d] = (query[d] + sum_j Wu[d][j] * r[t][j]) * score_w[d], bf16
// r[t][j] = (sum_ks r_part) * rsqrt(mean ssq + eps).  grid (128,4), 256 thr.
// r tile in LDS (broadcast reads), Wu row in registers.
// ---------------------------------------------------------------------------
__global__ __launch_bounds__(256) void k_qproj(const float* __restrict__ r_part,
                                               const float* __restrict__ ssq_part,
                                               const float* __restrict__ query,
                                               const float* __restrict__ score_w,
                                               const float* __restrict__ Wu,
                                               __hip_bfloat16* __restrict__ qs) {
    __shared__ float r_lds[64][68];

    int tid = threadIdx.x;
    int t0  = blockIdx.x * 64;
    int d   = blockIdx.y * 256 + tid;

    // stage r tile: thread handles token (tid>>2), 16 floats at (tid&3)*16
    {
        int tl = tid >> 2;
        int c0 = (tid & 3) * 16;
        int t  = t0 + tl;
        float sp = ssq_part[t] + ssq_part[TOKS + t] +
                   ssq_part[2 * (size_t)TOKS + t] + ssq_part[3 * (size_t)TOKS + t];
        float scale = rsqrtf(sp * (1.f / D_DIM) + EPSF);
        const float* rp = r_part + (size_t)t * 64 + c0;
#pragma unroll
        for (int p = 0; p < 4; ++p) {
            float4 v0 = *(const float4*)(rp + p * 4);
            float4 v1 = *(const float4*)(rp + (size_t)TOKS * 64 + p * 4);
            float4 v2 = *(const float4*)(rp + 2 * (size_t)TOKS * 64 + p * 4);
            float4 v3 = *(const float4*)(rp + 3 * (size_t)TOKS * 64 + p * 4);
            float4 s;
            s.x = (v0.x + v1.x + v2.x + v3.x) * scale;
            s.y = (v0.y + v1.y + v2.y + v3.y) * scale;
            s.z = (v0.z + v1.z + v2.z + v3.z) * scale;
            s.w = (v0.w + v1.w + v2.w + v3.w) * scale;
            *(float4*)&r_lds[tl][c0 + p * 4] = s;
        }
    }

    float4 wu[16];
    const float4* wr = (const float4*)(Wu + (size_t)d * 64);
#pragma unroll
    for (int m = 0; m < 16; ++m) wu[m] = wr[m];
    float qd  = query[d];
    float swd = score_w[d];
    __syncthreads();

    for (int t = 0; t < 64; ++t) {
        float a0 = 0.f, a1 = 0.f, a2 = 0.f, a3 = 0.f;
#pragma unroll
        for (int m = 0; m < 16; m += 4) {
            a0 += dot4(wu[m + 0], *(const float4*)&r_lds[t][(m + 0) * 4]);
            a1 += dot4(wu[m + 1], *(const float4*)&r_lds[t][(m + 1) * 4]);
            a2 += dot4(wu[m + 2], *(const float4*)&r_lds[t][(m + 2) * 4]);
            a3 += dot4(wu[m + 3], *(const float4*)&r_lds[t][(m + 3) * 4]);
        }
        float val = (qd + ((a0 + a1) + (a2 + a3))) * swd;
        qs[(size_t)(t0 + t) * D_DIM + d] = __float2bfloat16(val);
    }
}

// ---------------------------------------------------------------------------
// Main fused kernel: one block per (b,t) token. prev read ONCE (staged LDS).
// scores -> softmax(L) -> delta -> rmsnorm -> gated residual.
// ---------------------------------------------------------------------------
__global__ __launch_bounds__(256) void k_main(const float* __restrict__ h,
                                              const float* __restrict__ prev,
                                              const __hip_bfloat16* __restrict__ qs,
                                              const float* __restrict__ out_w,
                                              const float* __restrict__ tg_w,
                                              const float* __restrict__ gate,
                                              const float* __restrict__ tg_b,
                                              float* __restrict__ out,
                                              float* __restrict__ alpha_out) {
    __shared__ __align__(16) float pl[L_DIM][D_DIM];  // 32 KB staged prev rows
    __shared__ float wred[2][L_DIM][4];
    __shared__ float gred[4];
    __shared__ float dred[4];

    int tid = threadIdx.x, lane = tid & 63, w = tid >> 6;
    int blk = blockIdx.x;
    int b   = blk >> 11;
    int t   = blk & (T_DIM - 1);
    size_t tok = (size_t)blk;

    float4 h4 = ((const float4*)(h + tok * D_DIM))[tid];
    float4 tw = ((const float4*)tg_w)[tid];

    short4 qraw = *(const short4*)(qs + tok * D_DIM + tid * 4);
    float4 qv;
    qv.x = bf2f((unsigned short)qraw.x);
    qv.y = bf2f((unsigned short)qraw.y);
    qv.z = bf2f((unsigned short)qraw.z);
    qv.w = bf2f((unsigned short)qraw.w);

    float gp = wave_sum(dot4(h4, tw));
    if (lane == 0) gred[w] = gp;

#pragma unroll
    for (int l = 0; l < L_DIM; ++l) {
        float4 p = ((const float4*)(prev + ((size_t)((b * L_DIM + l) * T_DIM + t)) * D_DIM))[tid];
        ((float4*)pl[l])[tid] = p;
        float ssq = wave_sum(dot4(p, p));
        float dt  = wave_sum(dot4(p, qv));
        if (lane == 0) { wred[0][l][w] = ssq; wred[1][l][w] = dt; }
    }
    __syncthreads();

    float sc[L_DIM], mx = -1e30f;
#pragma unroll
    for (int l = 0; l < L_DIM; ++l) {
        float ssq = wred[0][l][0] + wred[0][l][1] + wred[0][l][2] + wred[0][l][3];
        float dt  = wred[1][l][0] + wred[1][l][1] + wred[1][l][2] + wred[1][l][3];
        sc[l] = dt * rsqrtf(ssq * (1.f / D_DIM) + EPSF);
        mx = fmaxf(mx, sc[l]);
    }
    float al[L_DIM], asum = 0.f;
#pragma unroll
    for (int l = 0; l < L_DIM; ++l) { al[l] = __expf(sc[l] - mx); asum += al[l]; }
    float inv = 1.f / asum;
#pragma unroll
    for (int l = 0; l < L_DIM; ++l) al[l] *= inv;

    float gd = gred[0] + gred[1] + gred[2] + gred[3];
    float g  = gate[0] / (1.f + __expf(-(gd + tg_b[0])));

    float4 dl = make_float4(0.f, 0.f, 0.f, 0.f);
#pragma unroll
    for (int l = 0; l < L_DIM; ++l) {
        float4 p = ((const float4*)pl[l])[tid];
        dl.x += al[l] * p.x; dl.y += al[l] * p.y;
        dl.z += al[l] * p.z; dl.w += al[l] * p.w;
    }
    float dss = wave_sum(dot4(dl, dl));
    if (lane == 0) dred[w] = dss;
    __syncthreads();
    float dsum   = dred[0] + dred[1] + dred[2] + dred[3];
    float dscale = rsqrtf(dsum * (1.f / D_DIM) + EPSF);

    float4 ow = ((const float4*)out_w)[tid];
    float4 o;
    o.x = h4.x + g * dl.x * dscale * ow.x;
    o.y = h4.y + g * dl.y * dscale * ow.y;
    o.z = h4.z + g * dl.z * dscale * ow.z;
    o.w = h4.w + g * dl.w * dscale * ow.w;
    ((float4*)(out + tok * D_DIM))[tid] = o;

    if (tid < L_DIM)
        alpha_out[(size_t)b * (L_DIM * T_DIM) + tid * T_DIM + t] = al[tid];
}

extern "C" void kernel_launch(void* const* d_in, const int* in_sizes, int n_in,
                              void* d_out, int out_size, void* d_ws, size_t ws_size,
                              hipStream_t stream) {
    (void)in_sizes; (void)n_in; (void)out_size; (void)ws_size;
    const float* h       = (const float*)d_in[0];
    const float* prev    = (const float*)d_in[1];
    const float* query   = (const float*)d_in[2];
    const float* gate    = (const float*)d_in[3];
    const float* score_w = (const float*)d_in[4];
    const float* out_w   = (const float*)d_in[5];
    const float* qnw     = (const float*)d_in[6];
    const float* Wd      = (const float*)d_in[7];
    const float* Wu      = (const float*)d_in[8];
    const float* tg_w    = (const float*)d_in[9];
    const float* tg_b    = (const float*)d_in[10];

    float* out   = (float*)d_out;
    float* alpha = out + OUT_ELEMS;

    // workspace layout (<= 24.2 MB):
    __hip_bfloat16* qsbuf = (__hip_bfloat16*)d_ws;                 // 16 MB
    float* r_part   = (float*)((char*)d_ws + (size_t)TOKS * D_DIM * 2);  // 8 MB
    float* ssq_part = r_part + (size_t)KSPLIT * TOKS * 64;               // 128 KB

    k_rproj<<<dim3(TOKS / G1_TT, KSPLIT), 256, 0, stream>>>(h, qnw, Wd, r_part, ssq_part);
    k_qproj<<<dim3(TOKS / 64, D_DIM / 256), 256, 0, stream>>>(r_part, ssq_part, query,
                                                              score_w, Wu, qsbuf);
    k_main<<<TOKS, 256, 0, stream>>>(h, prev, qsbuf, out_w, tg_w, gate, tg_b, out, alpha);
}

// Round 3
// 97.326 us; speedup vs baseline: 2.8812x; 1.5226x over previous
//
#include <hip/hip_runtime.h>
#include <hip/hip_bf16.h>

#define D_DIM 1024
#define L_DIM 8
#define T_DIM 2048
#define B_DIM 4
#define TOKS  (B_DIM * T_DIM)                 // 8192
#define OUT_ELEMS ((size_t)TOKS * D_DIM)      // 8388608
#define EPSF 1e-6f

typedef __attribute__((ext_vector_type(8)))  short short8_t;
typedef __attribute__((ext_vector_type(16))) float f32x16_t;

__device__ __forceinline__ float wave_sum(float v) {
#pragma unroll
    for (int off = 32; off; off >>= 1) v += __shfl_xor(v, off, 64);
    return v;
}

__device__ __forceinline__ float dot4(const float4& a, const float4& b) {
    return a.x * b.x + a.y * b.y + a.z * b.z + a.w * b.w;
}

__device__ __forceinline__ unsigned short f2bf(float f) {
    union { __hip_bfloat16 h; unsigned short u; } x;
    x.h = __float2bfloat16(f);
    return x.u;
}

__device__ __forceinline__ float bf2f(unsigned short u) {
    union { unsigned int i; float f; } x;
    x.i = ((unsigned int)u) << 16;
    return x.f;
}

// ---------------------------------------------------------------------------
// Prep: Wdq[j][k] = Wd[j][k] * qnw[k] as bf16;  Wubf = Wu as bf16.
// grid 64 x 256: each thread converts one float4 of each array.
// ---------------------------------------------------------------------------
__global__ __launch_bounds__(256) void k_prep(const float* __restrict__ Wd,
                                              const float* __restrict__ qnw,
                                              const float* __restrict__ Wu,
                                              unsigned short* __restrict__ Wdq,
                                              unsigned short* __restrict__ Wubf) {
    int i = (blockIdx.x * 256 + threadIdx.x) * 4;   // 0..65532
    float4 wd = *(const float4*)(Wd + i);
    float4 nv = *(const float4*)(qnw + (i & (D_DIM - 1)));
    short4 o1 = make_short4((short)f2bf(wd.x * nv.x), (short)f2bf(wd.y * nv.y),
                            (short)f2bf(wd.z * nv.z), (short)f2bf(wd.w * nv.w));
    *(short4*)(Wdq + i) = o1;
    float4 wu = *(const float4*)(Wu + i);
    short4 o2 = make_short4((short)f2bf(wu.x), (short)f2bf(wu.y),
                            (short)f2bf(wu.z), (short)f2bf(wu.w));
    *(short4*)(Wubf + i) = o2;
}

// ---------------------------------------------------------------------------
// Fused q kernel. One block = 32 tokens, 512 threads (8 waves).
// GEMM1: r[32t][64j] = h(bf16) x Wdq^T via MFMA, K=1024 split 8 ways (wave=kh).
//        A,B frags loaded DIRECTLY from global (no LDS stage). ssq folded in.
// Reduce K-partials + per-token rsqrt scale -> r tile bf16 in swizzled LDS.
// GEMM2: q[32t][1024d] = (query + Wu x r) * score_w -> bf16, B frags from L2.
// ---------------------------------------------------------------------------
__global__ __launch_bounds__(512) void k_q(const float* __restrict__ h,
                                           const unsigned short* __restrict__ Wdq,
                                           const unsigned short* __restrict__ Wubf,
                                           const float* __restrict__ query,
                                           const float* __restrict__ score_w,
                                           unsigned short* __restrict__ qs) {
    __shared__ float c_red[8][2][16][64];        // 64 KB K-split partials
    __shared__ float ssq_red[8][32];
    __shared__ float scale_sh[32];
    __shared__ unsigned short r_sw[32 * 64];     // 4 KB bf16, XOR-swizzled

    int tid  = threadIdx.x;
    int w    = tid >> 6;          // wave = K-split index
    int lane = tid & 63;
    int t0   = blockIdx.x * 32;

    // ---------------- GEMM1 ----------------
    f32x16_t acc0, acc1;
#pragma unroll
    for (int r = 0; r < 16; ++r) { acc0[r] = 0.f; acc1[r] = 0.f; }

    int arow = lane & 31;
    int koff = w * 128 + (lane >> 5) * 8;
    const float* hrow = h + (size_t)(t0 + arow) * D_DIM + koff;
    const unsigned short* b0 = Wdq + (size_t)arow * D_DIM + koff;
    const unsigned short* b1 = Wdq + (size_t)(32 + arow) * D_DIM + koff;

    float ssq = 0.f;
#pragma unroll
    for (int s = 0; s < 8; ++s) {
        float4 ha = *(const float4*)(hrow + s * 16);
        float4 hb = *(const float4*)(hrow + s * 16 + 4);
        ssq += dot4(ha, ha) + dot4(hb, hb);
        short8_t af;
        af[0] = (short)f2bf(ha.x); af[1] = (short)f2bf(ha.y);
        af[2] = (short)f2bf(ha.z); af[3] = (short)f2bf(ha.w);
        af[4] = (short)f2bf(hb.x); af[5] = (short)f2bf(hb.y);
        af[6] = (short)f2bf(hb.z); af[7] = (short)f2bf(hb.w);
        short8_t bf0 = *(const short8_t*)(b0 + s * 16);
        short8_t bf1 = *(const short8_t*)(b1 + s * 16);
        acc0 = __builtin_amdgcn_mfma_f32_32x32x16_bf16(af, bf0, acc0, 0, 0, 0);
        acc1 = __builtin_amdgcn_mfma_f32_32x32x16_bf16(af, bf1, acc1, 0, 0, 0);
    }

    ssq += __shfl_xor(ssq, 32, 64);
    if (lane < 32) ssq_red[w][lane] = ssq;
#pragma unroll
    for (int r = 0; r < 16; ++r) {
        c_red[w][0][r][lane] = acc0[r];
        c_red[w][1][r][lane] = acc1[r];
    }
    __syncthreads();

    if (tid < 32) {
        float s8 = 0.f;
#pragma unroll
        for (int u = 0; u < 8; ++u) s8 += ssq_red[u][tid];
        scale_sh[tid] = rsqrtf(s8 * (1.f / D_DIM) + EPSF);
    }
    __syncthreads();

    // pack r tile: sum 8 K-partials, scale, bf16, XOR-swizzle store
    for (int idx = tid; idx < 2048; idx += 512) {
        int nj = idx >> 10, rem = idx & 1023, reg = rem >> 6, ln = rem & 63;
        float v = 0.f;
#pragma unroll
        for (int u = 0; u < 8; ++u) v += c_red[u][nj][reg][ln];
        int tk = (reg & 3) + 8 * (reg >> 2) + 4 * (ln >> 5);
        int j  = nj * 32 + (ln & 31);
        v *= scale_sh[tk];
        int byte = (tk * 128 + j * 2) ^ ((tk & 7) << 4);
        r_sw[byte >> 1] = f2bf(v);
    }
    __syncthreads();

    // ---------------- GEMM2 ----------------
    short8_t afr[4];
#pragma unroll
    for (int s = 0; s < 4; ++s) {
        int tk = lane & 31;
        int k  = s * 16 + (lane >> 5) * 8;
        int byte = (tk * 128 + k * 2) ^ ((tk & 7) << 4);
        afr[s] = *(const short8_t*)(&r_sw[byte >> 1]);
    }

#pragma unroll
    for (int i = 0; i < 4; ++i) {
        int n0 = (w * 4 + i) * 32;
        int d  = n0 + (lane & 31);
        f32x16_t c;
#pragma unroll
        for (int r = 0; r < 16; ++r) c[r] = 0.f;
        const unsigned short* bb = Wubf + (size_t)d * 64 + (lane >> 5) * 8;
#pragma unroll
        for (int s = 0; s < 4; ++s) {
            short8_t bf = *(const short8_t*)(bb + s * 16);
            c = __builtin_amdgcn_mfma_f32_32x32x16_bf16(afr[s], bf, c, 0, 0, 0);
        }
        float qd  = query[d];
        float swd = score_w[d];
#pragma unroll
        for (int r = 0; r < 16; ++r) {
            int tk = (r & 3) + 8 * (r >> 2) + 4 * (lane >> 5);
            qs[(size_t)(t0 + tk) * D_DIM + d] = f2bf((qd + c[r]) * swd);
        }
    }
}

// ---------------------------------------------------------------------------
// Main fused kernel: one block per token; prev rows held in REGISTERS.
// ---------------------------------------------------------------------------
__global__ __launch_bounds__(256) void k_main(const float* __restrict__ h,
                                              const float* __restrict__ prev,
                                              const unsigned short* __restrict__ qs,
                                              const float* __restrict__ out_w,
                                              const float* __restrict__ tg_w,
                                              const float* __restrict__ gate,
                                              const float* __restrict__ tg_b,
                                              float* __restrict__ out,
                                              float* __restrict__ alpha_out) {
    __shared__ float wred[2][L_DIM][4];
    __shared__ float gred[4];
    __shared__ float dred[4];

    int tid = threadIdx.x, lane = tid & 63, w = tid >> 6;
    int blk = blockIdx.x;
    int b   = blk >> 11;
    int t   = blk & (T_DIM - 1);
    size_t tok = (size_t)blk;

    float4 h4 = ((const float4*)(h + tok * D_DIM))[tid];
    float4 tw = ((const float4*)tg_w)[tid];

    short4 qraw = *(const short4*)(qs + tok * D_DIM + tid * 4);
    float4 qv;
    qv.x = bf2f((unsigned short)qraw.x);
    qv.y = bf2f((unsigned short)qraw.y);
    qv.z = bf2f((unsigned short)qraw.z);
    qv.w = bf2f((unsigned short)qraw.w);

    float gp = wave_sum(dot4(h4, tw));
    if (lane == 0) gred[w] = gp;

    float4 p[L_DIM];
#pragma unroll
    for (int l = 0; l < L_DIM; ++l)
        p[l] = ((const float4*)(prev + ((size_t)((b * L_DIM + l) * T_DIM + t)) * D_DIM))[tid];

#pragma unroll
    for (int l = 0; l < L_DIM; ++l) {
        float ssq = wave_sum(dot4(p[l], p[l]));
        float dt  = wave_sum(dot4(p[l], qv));
        if (lane == 0) { wred[0][l][w] = ssq; wred[1][l][w] = dt; }
    }
    __syncthreads();

    float sc[L_DIM], mx = -1e30f;
#pragma unroll
    for (int l = 0; l < L_DIM; ++l) {
        float ssq = wred[0][l][0] + wred[0][l][1] + wred[0][l][2] + wred[0][l][3];
        float dt  = wred[1][l][0] + wred[1][l][1] + wred[1][l][2] + wred[1][l][3];
        sc[l] = dt * rsqrtf(ssq * (1.f / D_DIM) + EPSF);
        mx = fmaxf(mx, sc[l]);
    }
    float al[L_DIM], asum = 0.f;
#pragma unroll
    for (int l = 0; l < L_DIM; ++l) { al[l] = __expf(sc[l] - mx); asum += al[l]; }
    float inv = 1.f / asum;
#pragma unroll
    for (int l = 0; l < L_DIM; ++l) al[l] *= inv;

    float gd = gred[0] + gred[1] + gred[2] + gred[3];
    float g  = gate[0] / (1.f + __expf(-(gd + tg_b[0])));

    float4 dl = make_float4(0.f, 0.f, 0.f, 0.f);
#pragma unroll
    for (int l = 0; l < L_DIM; ++l) {
        dl.x += al[l] * p[l].x; dl.y += al[l] * p[l].y;
        dl.z += al[l] * p[l].z; dl.w += al[l] * p[l].w;
    }
    float dss = wave_sum(dot4(dl, dl));
    if (lane == 0) dred[w] = dss;
    __syncthreads();
    float dsum   = dred[0] + dred[1] + dred[2] + dred[3];
    float dscale = rsqrtf(dsum * (1.f / D_DIM) + EPSF);

    float4 ow = ((const float4*)out_w)[tid];
    float4 o;
    o.x = h4.x + g * dl.x * dscale * ow.x;
    o.y = h4.y + g * dl.y * dscale * ow.y;
    o.z = h4.z + g * dl.z * dscale * ow.z;
    o.w = h4.w + g * dl.w * dscale * ow.w;
    ((float4*)(out + tok * D_DIM))[tid] = o;

    if (tid < L_DIM)
        alpha_out[(size_t)b * (L_DIM * T_DIM) + tid * T_DIM + t] = al[tid];
}

extern "C" void kernel_launch(void* const* d_in, const int* in_sizes, int n_in,
                              void* d_out, int out_size, void* d_ws, size_t ws_size,
                              hipStream_t stream) {
    (void)in_sizes; (void)n_in; (void)out_size; (void)ws_size;
    const float* h       = (const float*)d_in[0];
    const float* prev    = (const float*)d_in[1];
    const float* query   = (const float*)d_in[2];
    const float* gate    = (const float*)d_in[3];
    const float* score_w = (const float*)d_in[4];
    const float* out_w   = (const float*)d_in[5];
    const float* qnw     = (const float*)d_in[6];
    const float* Wd      = (const float*)d_in[7];
    const float* Wu      = (const float*)d_in[8];
    const float* tg_w    = (const float*)d_in[9];
    const float* tg_b    = (const float*)d_in[10];

    float* out   = (float*)d_out;
    float* alpha = out + OUT_ELEMS;

    // workspace: qs bf16 (16 MB) | Wdq bf16 (128 KB) | Wubf bf16 (128 KB)
    unsigned short* qsbuf = (unsigned short*)d_ws;
    unsigned short* Wdq   = qsbuf + OUT_ELEMS;
    unsigned short* Wubf  = Wdq + (size_t)64 * D_DIM;

    k_prep<<<64, 256, 0, stream>>>(Wd, qnw, Wu, Wdq, Wubf);
    k_q<<<TOKS / 32, 512, 0, stream>>>(h, Wdq, Wubf, query, score_w, qsbuf);
    k_main<<<TOKS, 256, 0, stream>>>(h, prev, qsbuf, out_w, tg_w, gate, tg_b, out, alpha);
}

// Round 4
// 91.439 us; speedup vs baseline: 3.0666x; 1.0644x over previous
//
#include <hip/hip_runtime.h>
#include <hip/hip_bf16.h>

#define D_DIM 1024
#define L_DIM 8
#define T_DIM 2048
#define B_DIM 4
#define TOKS  (B_DIM * T_DIM)                 // 8192
#define OUT_ELEMS ((size_t)TOKS * D_DIM)      // 8388608
#define EPSF 1e-6f

typedef __attribute__((ext_vector_type(8)))  short short8_t;
typedef __attribute__((ext_vector_type(16))) float f32x16_t;

__device__ __forceinline__ float wave_sum(float v) {
#pragma unroll
    for (int off = 32; off; off >>= 1) v += __shfl_xor(v, off, 64);
    return v;
}

__device__ __forceinline__ float dot4(const float4& a, const float4& b) {
    return a.x * b.x + a.y * b.y + a.z * b.z + a.w * b.w;
}

__device__ __forceinline__ unsigned short f2bf(float f) {
    union { __hip_bfloat16 h; unsigned short u; } x;
    x.h = __float2bfloat16(f);
    return x.u;
}

__device__ __forceinline__ float bf2f(unsigned short u) {
    union { unsigned int i; float f; } x;
    x.i = ((unsigned int)u) << 16;
    return x.f;
}

// ---------------------------------------------------------------------------
// Prep: Wdq[j][k] = Wd[j][k] * qnw[k] as bf16;  Wubf = Wu as bf16.
// ---------------------------------------------------------------------------
__global__ __launch_bounds__(256) void k_prep(const float* __restrict__ Wd,
                                              const float* __restrict__ qnw,
                                              const float* __restrict__ Wu,
                                              unsigned short* __restrict__ Wdq,
                                              unsigned short* __restrict__ Wubf) {
    int i = (blockIdx.x * 256 + threadIdx.x) * 4;
    float4 wd = *(const float4*)(Wd + i);
    float4 nv = *(const float4*)(qnw + (i & (D_DIM - 1)));
    short4 o1 = make_short4((short)f2bf(wd.x * nv.x), (short)f2bf(wd.y * nv.y),
                            (short)f2bf(wd.z * nv.z), (short)f2bf(wd.w * nv.w));
    *(short4*)(Wdq + i) = o1;
    float4 wu = *(const float4*)(Wu + i);
    short4 o2 = make_short4((short)f2bf(wu.x), (short)f2bf(wu.y),
                            (short)f2bf(wu.z), (short)f2bf(wu.w));
    *(short4*)(Wubf + i) = o2;
}

// ---------------------------------------------------------------------------
// Fused q kernel (unchanged from R2): 32 tokens/block, 512 thr, MFMA GEMMs.
// ---------------------------------------------------------------------------
__global__ __launch_bounds__(512) void k_q(const float* __restrict__ h,
                                           const unsigned short* __restrict__ Wdq,
                                           const unsigned short* __restrict__ Wubf,
                                           const float* __restrict__ query,
                                           const float* __restrict__ score_w,
                                           unsigned short* __restrict__ qs) {
    __shared__ float c_red[8][2][16][64];
    __shared__ float ssq_red[8][32];
    __shared__ float scale_sh[32];
    __shared__ unsigned short r_sw[32 * 64];

    int tid  = threadIdx.x;
    int w    = tid >> 6;
    int lane = tid & 63;
    int t0   = blockIdx.x * 32;

    f32x16_t acc0, acc1;
#pragma unroll
    for (int r = 0; r < 16; ++r) { acc0[r] = 0.f; acc1[r] = 0.f; }

    int arow = lane & 31;
    int koff = w * 128 + (lane >> 5) * 8;
    const float* hrow = h + (size_t)(t0 + arow) * D_DIM + koff;
    const unsigned short* b0 = Wdq + (size_t)arow * D_DIM + koff;
    const unsigned short* b1 = Wdq + (size_t)(32 + arow) * D_DIM + koff;

    float ssq = 0.f;
#pragma unroll
    for (int s = 0; s < 8; ++s) {
        float4 ha = *(const float4*)(hrow + s * 16);
        float4 hb = *(const float4*)(hrow + s * 16 + 4);
        ssq += dot4(ha, ha) + dot4(hb, hb);
        short8_t af;
        af[0] = (short)f2bf(ha.x); af[1] = (short)f2bf(ha.y);
        af[2] = (short)f2bf(ha.z); af[3] = (short)f2bf(ha.w);
        af[4] = (short)f2bf(hb.x); af[5] = (short)f2bf(hb.y);
        af[6] = (short)f2bf(hb.z); af[7] = (short)f2bf(hb.w);
        short8_t bf0 = *(const short8_t*)(b0 + s * 16);
        short8_t bf1 = *(const short8_t*)(b1 + s * 16);
        acc0 = __builtin_amdgcn_mfma_f32_32x32x16_bf16(af, bf0, acc0, 0, 0, 0);
        acc1 = __builtin_amdgcn_mfma_f32_32x32x16_bf16(af, bf1, acc1, 0, 0, 0);
    }

    ssq += __shfl_xor(ssq, 32, 64);
    if (lane < 32) ssq_red[w][lane] = ssq;
#pragma unroll
    for (int r = 0; r < 16; ++r) {
        c_red[w][0][r][lane] = acc0[r];
        c_red[w][1][r][lane] = acc1[r];
    }
    __syncthreads();

    if (tid < 32) {
        float s8 = 0.f;
#pragma unroll
        for (int u = 0; u < 8; ++u) s8 += ssq_red[u][tid];
        scale_sh[tid] = rsqrtf(s8 * (1.f / D_DIM) + EPSF);
    }
    __syncthreads();

    for (int idx = tid; idx < 2048; idx += 512) {
        int nj = idx >> 10, rem = idx & 1023, reg = rem >> 6, ln = rem & 63;
        float v = 0.f;
#pragma unroll
        for (int u = 0; u < 8; ++u) v += c_red[u][nj][reg][ln];
        int tk = (reg & 3) + 8 * (reg >> 2) + 4 * (ln >> 5);
        int j  = nj * 32 + (ln & 31);
        v *= scale_sh[tk];
        int byte = (tk * 128 + j * 2) ^ ((tk & 7) << 4);
        r_sw[byte >> 1] = f2bf(v);
    }
    __syncthreads();

    short8_t afr[4];
#pragma unroll
    for (int s = 0; s < 4; ++s) {
        int tk = lane & 31;
        int k  = s * 16 + (lane >> 5) * 8;
        int byte = (tk * 128 + k * 2) ^ ((tk & 7) << 4);
        afr[s] = *(const short8_t*)(&r_sw[byte >> 1]);
    }

#pragma unroll
    for (int i = 0; i < 4; ++i) {
        int n0 = (w * 4 + i) * 32;
        int d  = n0 + (lane & 31);
        f32x16_t c;
#pragma unroll
        for (int r = 0; r < 16; ++r) c[r] = 0.f;
        const unsigned short* bb = Wubf + (size_t)d * 64 + (lane >> 5) * 8;
#pragma unroll
        for (int s = 0; s < 4; ++s) {
            short8_t bf = *(const short8_t*)(bb + s * 16);
            c = __builtin_amdgcn_mfma_f32_32x32x16_bf16(afr[s], bf, c, 0, 0, 0);
        }
        float qd  = query[d];
        float swd = score_w[d];
#pragma unroll
        for (int r = 0; r < 16; ++r) {
            int tk = (r & 3) + 8 * (r >> 2) + 4 * (lane >> 5);
            qs[(size_t)(t0 + tk) * D_DIM + d] = f2bf((qd + c[r]) * swd);
        }
    }
}

// ---------------------------------------------------------------------------
// Main kernel: one block per token; prev in REGISTERS; LDS-transpose reduce.
// ---------------------------------------------------------------------------
__global__ __launch_bounds__(256) void k_main(const float* __restrict__ h,
                                              const float* __restrict__ prev,
                                              const unsigned short* __restrict__ qs,
                                              const float* __restrict__ out_w,
                                              const float* __restrict__ tg_w,
                                              const float* __restrict__ gate,
                                              const float* __restrict__ tg_b,
                                              float* __restrict__ out,
                                              float* __restrict__ alpha_out) {
    __shared__ float red[16][264];   // 16 per-l partial rows, 2-way-max banks
    __shared__ float fin[16];
    __shared__ float gred[4];
    __shared__ float dred[4];

    int tid = threadIdx.x, lane = tid & 63, w = tid >> 6;
    int blk = blockIdx.x;
    int b   = blk >> 11;
    int t   = blk & (T_DIM - 1);
    size_t tok = (size_t)blk;

    // prev loads first — start the big HBM stream immediately
    const float* pbase = prev + ((size_t)(b * L_DIM) * T_DIM + t) * D_DIM;
    float4 p[L_DIM];
#pragma unroll
    for (int l = 0; l < L_DIM; ++l)
        p[l] = ((const float4*)(pbase + (size_t)l * T_DIM * D_DIM))[tid];

    float4 h4 = ((const float4*)(h + tok * D_DIM))[tid];
    short4 qraw = *(const short4*)(qs + tok * D_DIM + tid * 4);
    float4 qv;
    qv.x = bf2f((unsigned short)qraw.x);
    qv.y = bf2f((unsigned short)qraw.y);
    qv.z = bf2f((unsigned short)qraw.z);
    qv.w = bf2f((unsigned short)qraw.w);
    float4 tw = ((const float4*)tg_w)[tid];

    float gp = wave_sum(dot4(h4, tw));
    if (lane == 0) gred[w] = gp;

    // 16 per-l partials -> LDS (conflict-free column writes)
#pragma unroll
    for (int l = 0; l < L_DIM; ++l) {
        red[l][tid]         = dot4(p[l], p[l]);
        red[l + 8][tid]     = dot4(p[l], qv);
    }
    __syncthreads();

    // cooperative transpose-reduce: value v = tid>>4, segment seg = tid&15
    {
        int v = tid >> 4, seg = tid & 15;
        float s = 0.f;
#pragma unroll
        for (int i = 0; i < 16; ++i) s += red[v][seg + 16 * i];
#pragma unroll
        for (int off = 1; off < 16; off <<= 1) s += __shfl_xor(s, off, 64);
        if (seg == 0) fin[v] = s;
    }
    __syncthreads();

    float sc[L_DIM], mx = -1e30f;
#pragma unroll
    for (int l = 0; l < L_DIM; ++l) {
        sc[l] = fin[l + 8] * rsqrtf(fin[l] * (1.f / D_DIM) + EPSF);
        mx = fmaxf(mx, sc[l]);
    }
    float al[L_DIM], asum = 0.f;
#pragma unroll
    for (int l = 0; l < L_DIM; ++l) { al[l] = __expf(sc[l] - mx); asum += al[l]; }
    float inv = 1.f / asum;
#pragma unroll
    for (int l = 0; l < L_DIM; ++l) al[l] *= inv;

    float gd = gred[0] + gred[1] + gred[2] + gred[3];
    float g  = gate[0] / (1.f + __expf(-(gd + tg_b[0])));

    float4 dl = make_float4(0.f, 0.f, 0.f, 0.f);
#pragma unroll
    for (int l = 0; l < L_DIM; ++l) {
        dl.x += al[l] * p[l].x; dl.y += al[l] * p[l].y;
        dl.z += al[l] * p[l].z; dl.w += al[l] * p[l].w;
    }
    float dss = wave_sum(dot4(dl, dl));
    if (lane == 0) dred[w] = dss;
    __syncthreads();
    float dsum   = dred[0] + dred[1] + dred[2] + dred[3];
    float dscale = rsqrtf(dsum * (1.f / D_DIM) + EPSF);

    float4 ow = ((const float4*)out_w)[tid];
    float4 o;
    o.x = h4.x + g * dl.x * dscale * ow.x;
    o.y = h4.y + g * dl.y * dscale * ow.y;
    o.z = h4.z + g * dl.z * dscale * ow.z;
    o.w = h4.w + g * dl.w * dscale * ow.w;
    ((float4*)(out + tok * D_DIM))[tid] = o;

    if (tid < L_DIM)
        alpha_out[(size_t)b * (L_DIM * T_DIM) + tid * T_DIM + t] = al[tid];
}

extern "C" void kernel_launch(void* const* d_in, const int* in_sizes, int n_in,
                              void* d_out, int out_size, void* d_ws, size_t ws_size,
                              hipStream_t stream) {
    (void)in_sizes; (void)n_in; (void)out_size; (void)ws_size;
    const float* h       = (const float*)d_in[0];
    const float* prev    = (const float*)d_in[1];
    const float* query   = (const float*)d_in[2];
    const float* gate    = (const float*)d_in[3];
    const float* score_w = (const float*)d_in[4];
    const float* out_w   = (const float*)d_in[5];
    const float* qnw     = (const float*)d_in[6];
    const float* Wd      = (const float*)d_in[7];
    const float* Wu      = (const float*)d_in[8];
    const float* tg_w    = (const float*)d_in[9];
    const float* tg_b    = (const float*)d_in[10];

    float* out   = (float*)d_out;
    float* alpha = out + OUT_ELEMS;

    unsigned short* qsbuf = (unsigned short*)d_ws;
    unsigned short* Wdq   = qsbuf + OUT_ELEMS;
    unsigned short* Wubf  = Wdq + (size_t)64 * D_DIM;

    k_prep<<<64, 256, 0, stream>>>(Wd, qnw, Wu, Wdq, Wubf);
    k_q<<<TOKS / 32, 512, 0, stream>>>(h, Wdq, Wubf, query, score_w, qsbuf);
    k_main<<<TOKS, 256, 0, stream>>>(h, prev, qsbuf, out_w, tg_w, gate, tg_b, out, alpha);
}

// Round 6
// 90.439 us; speedup vs baseline: 3.1006x; 1.0111x over previous
//
#include <hip/hip_runtime.h>
#include <hip/hip_bf16.h>

#define D_DIM 1024
#define L_DIM 8
#define T_DIM 2048
#define B_DIM 4
#define TOKS  (B_DIM * T_DIM)                 // 8192
#define OUT_ELEMS ((size_t)TOKS * D_DIM)      // 8388608
#define EPSF 1e-6f

typedef __attribute__((ext_vector_type(8)))  short short8_t;
typedef __attribute__((ext_vector_type(16))) float f32x16_t;
typedef __attribute__((ext_vector_type(4)))  float f32x4_t;

// qt overlay: 32 rows, stride 1048 u16 (2096 B) -> halves hit disjoint banks
#define QT_STRIDE 1048

__device__ __forceinline__ float wave_sum(float v) {
#pragma unroll
    for (int off = 32; off; off >>= 1) v += __shfl_xor(v, off, 64);
    return v;
}

__device__ __forceinline__ float dot4v(const f32x4_t& a, const f32x4_t& b) {
    return a.x * b.x + a.y * b.y + a.z * b.z + a.w * b.w;
}

__device__ __forceinline__ unsigned short f2bf(float f) {
    union { __hip_bfloat16 h; unsigned short u; } x;
    x.h = __float2bfloat16(f);
    return x.u;
}

__device__ __forceinline__ float bf2f(unsigned short u) {
    union { unsigned int i; float f; } x;
    x.i = ((unsigned int)u) << 16;
    return x.f;
}

// ---------------------------------------------------------------------------
// Prep: Wdq[j][k] = Wd[j][k] * qnw[k] as bf16;  Wubf = Wu as bf16.
// ---------------------------------------------------------------------------
__global__ __launch_bounds__(256) void k_prep(const float* __restrict__ Wd,
                                              const float* __restrict__ qnw,
                                              const float* __restrict__ Wu,
                                              unsigned short* __restrict__ Wdq,
                                              unsigned short* __restrict__ Wubf) {
    int i = (blockIdx.x * 256 + threadIdx.x) * 4;
    float4 wd = *(const float4*)(Wd + i);
    float4 nv = *(const float4*)(qnw + (i & (D_DIM - 1)));
    short4 o1 = make_short4((short)f2bf(wd.x * nv.x), (short)f2bf(wd.y * nv.y),
                            (short)f2bf(wd.z * nv.z), (short)f2bf(wd.w * nv.w));
    *(short4*)(Wdq + i) = o1;
    float4 wu = *(const float4*)(Wu + i);
    short4 o2 = make_short4((short)f2bf(wu.x), (short)f2bf(wu.y),
                            (short)f2bf(wu.z), (short)f2bf(wu.w));
    *(short4*)(Wubf + i) = o2;
}

// ---------------------------------------------------------------------------
// Fused q kernel: 32 tokens/block, 512 thr, MFMA GEMMs.
// GEMM2 output transposed through LDS -> coalesced 16B qs stores.
// ---------------------------------------------------------------------------
__global__ __launch_bounds__(512) void k_q(const float* __restrict__ h,
                                           const unsigned short* __restrict__ Wdq,
                                           const unsigned short* __restrict__ Wubf,
                                           const float* __restrict__ query,
                                           const float* __restrict__ score_w,
                                           unsigned short* __restrict__ qs) {
    __shared__ __align__(16) char smem[70784];
    float (*c_red)[2][16][64] = (float (*)[2][16][64])smem;               // 64 KB
    float (*ssq_red)[32]      = (float (*)[32])(smem + 65536);            // 1 KB
    float* scale_sh           = (float*)(smem + 66560);                   // 128 B
    unsigned short* r_sw      = (unsigned short*)(smem + 66688);          // 4 KB
    unsigned short* qt        = (unsigned short*)smem;                    // overlay 67 KB

    int tid  = threadIdx.x;
    int w    = tid >> 6;
    int lane = tid & 63;
    int t0   = blockIdx.x * 32;

    // ---------------- GEMM1 ----------------
    f32x16_t acc0, acc1;
#pragma unroll
    for (int r = 0; r < 16; ++r) { acc0[r] = 0.f; acc1[r] = 0.f; }

    int arow = lane & 31;
    int koff = w * 128 + (lane >> 5) * 8;
    const float* hrow = h + (size_t)(t0 + arow) * D_DIM + koff;
    const unsigned short* b0 = Wdq + (size_t)arow * D_DIM + koff;
    const unsigned short* b1 = Wdq + (size_t)(32 + arow) * D_DIM + koff;

    float ssq = 0.f;
#pragma unroll
    for (int s = 0; s < 8; ++s) {
        f32x4_t ha = *(const f32x4_t*)(hrow + s * 16);
        f32x4_t hb = *(const f32x4_t*)(hrow + s * 16 + 4);
        ssq += dot4v(ha, ha) + dot4v(hb, hb);
        short8_t af;
        af[0] = (short)f2bf(ha.x); af[1] = (short)f2bf(ha.y);
        af[2] = (short)f2bf(ha.z); af[3] = (short)f2bf(ha.w);
        af[4] = (short)f2bf(hb.x); af[5] = (short)f2bf(hb.y);
        af[6] = (short)f2bf(hb.z); af[7] = (short)f2bf(hb.w);
        short8_t bf0 = *(const short8_t*)(b0 + s * 16);
        short8_t bf1 = *(const short8_t*)(b1 + s * 16);
        acc0 = __builtin_amdgcn_mfma_f32_32x32x16_bf16(af, bf0, acc0, 0, 0, 0);
        acc1 = __builtin_amdgcn_mfma_f32_32x32x16_bf16(af, bf1, acc1, 0, 0, 0);
    }

    ssq += __shfl_xor(ssq, 32, 64);
    if (lane < 32) ssq_red[w][lane] = ssq;
#pragma unroll
    for (int r = 0; r < 16; ++r) {
        c_red[w][0][r][lane] = acc0[r];
        c_red[w][1][r][lane] = acc1[r];
    }
    __syncthreads();

    if (tid < 32) {
        float s8 = 0.f;
#pragma unroll
        for (int u = 0; u < 8; ++u) s8 += ssq_red[u][tid];
        scale_sh[tid] = rsqrtf(s8 * (1.f / D_DIM) + EPSF);
    }
    __syncthreads();

    // pack r tile: sum 8 K-partials, scale, bf16, XOR-swizzle store
    for (int idx = tid; idx < 2048; idx += 512) {
        int nj = idx >> 10, rem = idx & 1023, reg = rem >> 6, ln = rem & 63;
        float v = 0.f;
#pragma unroll
        for (int u = 0; u < 8; ++u) v += c_red[u][nj][reg][ln];
        int tk = (reg & 3) + 8 * (reg >> 2) + 4 * (ln >> 5);
        int j  = nj * 32 + (ln & 31);
        v *= scale_sh[tk];
        int byte = (tk * 128 + j * 2) ^ ((tk & 7) << 4);
        r_sw[byte >> 1] = f2bf(v);
    }
    __syncthreads();

    // ---------------- GEMM2 ----------------
    short8_t afr[4];
#pragma unroll
    for (int s = 0; s < 4; ++s) {
        int tk = lane & 31;
        int k  = s * 16 + (lane >> 5) * 8;
        int byte = (tk * 128 + k * 2) ^ ((tk & 7) << 4);
        afr[s] = *(const short8_t*)(&r_sw[byte >> 1]);
    }
    __syncthreads();   // afr in regs; c_red/r_sw region now reusable as qt

#pragma unroll
    for (int i = 0; i < 4; ++i) {
        int n0 = (w * 4 + i) * 32;
        int d  = n0 + (lane & 31);
        f32x16_t c;
#pragma unroll
        for (int r = 0; r < 16; ++r) c[r] = 0.f;
        const unsigned short* bb = Wubf + (size_t)d * 64 + (lane >> 5) * 8;
#pragma unroll
        for (int s = 0; s < 4; ++s) {
            short8_t bf = *(const short8_t*)(bb + s * 16);
            c = __builtin_amdgcn_mfma_f32_32x32x16_bf16(afr[s], bf, c, 0, 0, 0);
        }
        float qd  = query[d];
        float swd = score_w[d];
#pragma unroll
        for (int r = 0; r < 16; ++r) {
            int tk = (r & 3) + 8 * (r >> 2) + 4 * (lane >> 5);
            unsigned int v = f2bf((qd + c[r]) * swd);
            unsigned int pv = (unsigned int)__shfl_xor((int)v, 1, 64);
            if ((lane & 1) == 0) {
                unsigned int word = (v & 0xffffu) | (pv << 16);
                *(unsigned int*)&qt[tk * QT_STRIDE + d] = word;
            }
        }
    }
    __syncthreads();

    // coalesced readout: 16B per store, 8 stores/thread (128 chunks/row!)
#pragma unroll
    for (int j = 0; j < 8; ++j) {
        int row   = tid >> 4;
        int chunk = (tid & 15) + j * 16;             // 0..127 (16B units)
        short8_t v = *(const short8_t*)&qt[row * QT_STRIDE + chunk * 8];
        *(short8_t*)(qs + (size_t)(t0 + row) * D_DIM + chunk * 8) = v;
    }
}

// ---------------------------------------------------------------------------
// Main kernel: one block per token; prev in REGISTERS (nontemporal loads);
// LDS-transpose reduce; nontemporal out store.
// ---------------------------------------------------------------------------
__global__ __launch_bounds__(256) void k_main(const float* __restrict__ h,
                                              const float* __restrict__ prev,
                                              const unsigned short* __restrict__ qs,
                                              const float* __restrict__ out_w,
                                              const float* __restrict__ tg_w,
                                              const float* __restrict__ gate,
                                              const float* __restrict__ tg_b,
                                              float* __restrict__ out,
                                              float* __restrict__ alpha_out) {
    __shared__ float red[16][264];
    __shared__ float fin[16];
    __shared__ float gred[4];
    __shared__ float dred[4];

    int tid = threadIdx.x, lane = tid & 63, w = tid >> 6;
    int blk = blockIdx.x;
    int b   = blk >> 11;
    int t   = blk & (T_DIM - 1);
    size_t tok = (size_t)blk;

    // prev loads first (nontemporal: stream once, don't evict h/qs from L3)
    const float* pbase = prev + ((size_t)(b * L_DIM) * T_DIM + t) * D_DIM;
    f32x4_t p[L_DIM];
#pragma unroll
    for (int l = 0; l < L_DIM; ++l)
        p[l] = __builtin_nontemporal_load(((const f32x4_t*)(pbase + (size_t)l * T_DIM * D_DIM)) + tid);

    f32x4_t h4 = ((const f32x4_t*)(h + tok * D_DIM))[tid];
    short4 qraw = *(const short4*)(qs + tok * D_DIM + tid * 4);
    f32x4_t qv;
    qv.x = bf2f((unsigned short)qraw.x);
    qv.y = bf2f((unsigned short)qraw.y);
    qv.z = bf2f((unsigned short)qraw.z);
    qv.w = bf2f((unsigned short)qraw.w);
    f32x4_t tw = ((const f32x4_t*)tg_w)[tid];

    float gp = wave_sum(dot4v(h4, tw));
    if (lane == 0) gred[w] = gp;

#pragma unroll
    for (int l = 0; l < L_DIM; ++l) {
        red[l][tid]     = dot4v(p[l], p[l]);
        red[l + 8][tid] = dot4v(p[l], qv);
    }
    __syncthreads();

    {
        int v = tid >> 4, seg = tid & 15;
        float s = 0.f;
#pragma unroll
        for (int i = 0; i < 16; ++i) s += red[v][seg + 16 * i];
#pragma unroll
        for (int off = 1; off < 16; off <<= 1) s += __shfl_xor(s, off, 64);
        if (seg == 0) fin[v] = s;
    }
    __syncthreads();

    float sc[L_DIM], mx = -1e30f;
#pragma unroll
    for (int l = 0; l < L_DIM; ++l) {
        sc[l] = fin[l + 8] * rsqrtf(fin[l] * (1.f / D_DIM) + EPSF);
        mx = fmaxf(mx, sc[l]);
    }
    float al[L_DIM], asum = 0.f;
#pragma unroll
    for (int l = 0; l < L_DIM; ++l) { al[l] = __expf(sc[l] - mx); asum += al[l]; }
    float inv = 1.f / asum;
#pragma unroll
    for (int l = 0; l < L_DIM; ++l) al[l] *= inv;

    float gd = gred[0] + gred[1] + gred[2] + gred[3];
    float g  = gate[0] / (1.f + __expf(-(gd + tg_b[0])));

    f32x4_t dl = {0.f, 0.f, 0.f, 0.f};
#pragma unroll
    for (int l = 0; l < L_DIM; ++l) {
        dl.x += al[l] * p[l].x; dl.y += al[l] * p[l].y;
        dl.z += al[l] * p[l].z; dl.w += al[l] * p[l].w;
    }
    float dss = wave_sum(dot4v(dl, dl));
    if (lane == 0) dred[w] = dss;
    __syncthreads();
    float dsum   = dred[0] + dred[1] + dred[2] + dred[3];
    float dscale = rsqrtf(dsum * (1.f / D_DIM) + EPSF);

    f32x4_t ow = ((const f32x4_t*)out_w)[tid];
    f32x4_t o;
    o.x = h4.x + g * dl.x * dscale * ow.x;
    o.y = h4.y + g * dl.y * dscale * ow.y;
    o.z = h4.z + g * dl.z * dscale * ow.z;
    o.w = h4.w + g * dl.w * dscale * ow.w;
    __builtin_nontemporal_store(o, ((f32x4_t*)(out + tok * D_DIM)) + tid);

    if (tid < L_DIM)
        alpha_out[(size_t)b * (L_DIM * T_DIM) + tid * T_DIM + t] = al[tid];
}

extern "C" void kernel_launch(void* const* d_in, const int* in_sizes, int n_in,
                              void* d_out, int out_size, void* d_ws, size_t ws_size,
                              hipStream_t stream) {
    (void)in_sizes; (void)n_in; (void)out_size; (void)ws_size;
    const float* h       = (const float*)d_in[0];
    const float* prev    = (const float*)d_in[1];
    const float* query   = (const float*)d_in[2];
    const float* gate    = (const float*)d_in[3];
    const float* score_w = (const float*)d_in[4];
    const float* out_w   = (const float*)d_in[5];
    const float* qnw     = (const float*)d_in[6];
    const float* Wd      = (const float*)d_in[7];
    const float* Wu      = (const float*)d_in[8];
    const float* tg_w    = (const float*)d_in[9];
    const float* tg_b    = (const float*)d_in[10];

    float* out   = (float*)d_out;
    float* alpha = out + OUT_ELEMS;

    unsigned short* qsbuf = (unsigned short*)d_ws;
    unsigned short* Wdq   = qsbuf + OUT_ELEMS;
    unsigned short* Wubf  = Wdq + (size_t)64 * D_DIM;

    k_prep<<<64, 256, 0, stream>>>(Wd, qnw, Wu, Wdq, Wubf);
    k_q<<<TOKS / 32, 512, 0, stream>>>(h, Wdq, Wubf, query, score_w, qsbuf);
    k_main<<<TOKS, 256, 0, stream>>>(h, prev, qsbuf, out_w, tg_w, gate, tg_b, out, alpha);
}